// Round 5
// baseline (228.834 us; speedup 1.0000x reference)
//
#include <hip/hip_runtime.h>
#include <math.h>

#define EDIM 128
#define NHEAD 16
#define HDIM 8
#define SEQ 2048
#define BATCH 4
#define NROW (BATCH*SEQ)            // 8192
// -scale*log2(e): folded into Q at projection time so sigmoid = rcp(1+exp2(dot))
#define QNEG (-0.35355339059327373f * 1.4426950408889634f)

#if __has_builtin(__builtin_amdgcn_exp2f)
#define EXP2F(x) __builtin_amdgcn_exp2f(x)
#else
#define EXP2F(x) exp2f(x)
#endif
#define RCPF(x) __builtin_amdgcn_rcpf(x)

typedef __attribute__((ext_vector_type(8))) short short8v;
typedef __attribute__((ext_vector_type(4))) short short4v;
typedef __attribute__((ext_vector_type(4))) float float4v;

union U16x8 { uint4 u; short8v s; };
union U16x4 { uint2 u; short4v s; };

#if __has_builtin(__builtin_amdgcn_mfma_f32_16x16x16bf16_1k)
#define MFMA_PV(a,b,c) __builtin_amdgcn_mfma_f32_16x16x16bf16_1k(a,b,c,0,0,0)
#else
static __device__ __forceinline__ float4v mfma_pv_asm(short4v a, short4v b, float4v c) {
  float4v d;
  asm("v_mfma_f32_16x16x16_bf16 %0, %1, %2, %3" : "=v"(d) : "v"(a), "v"(b), "v"(c));
  return d;
}
#define MFMA_PV(a,b,c) mfma_pv_asm(a,b,c)
#endif

// pack two floats to bf16x2, round-to-nearest-even (values finite)
__device__ __forceinline__ unsigned pk_bf16(float a, float b) {
  unsigned ua = __float_as_uint(a), ub = __float_as_uint(b);
  unsigned lo = (ua + 0x7fffu + ((ua >> 16) & 1u)) >> 16;
  unsigned hi = (ub + 0x7fffu + ((ub >> 16) & 1u)) & 0xffff0000u;
  return lo | hi;
}
__device__ __forceinline__ unsigned short pk_bf16_1(float a) {
  unsigned ua = __float_as_uint(a);
  return (unsigned short)((ua + 0x7fffu + ((ua >> 16) & 1u)) >> 16);
}

// ---------------------------------------------------------------------------
// Transpose the 4 weight matrices W[j][i] -> WT[i][j].
// ---------------------------------------------------------------------------
__global__ __launch_bounds__(256)
void transpose4_kernel(const float* __restrict__ W0, const float* __restrict__ W1,
                       const float* __restrict__ W2, const float* __restrict__ W3,
                       float* __restrict__ WT)
{
  const float* W = (blockIdx.y == 0) ? W0 : (blockIdx.y == 1) ? W1
                 : (blockIdx.y == 2) ? W2 : W3;
  float* out = WT + blockIdx.y * EDIM * EDIM;
  const int i0 = blockIdx.x * 16;
  #pragma unroll
  for (int it = 0; it < 8; ++it) {
    int f = threadIdx.x + it * 256;
    int i = i0 + (f >> 7);
    int j = f & 127;
    out[i * EDIM + j] = W[j * EDIM + i];
  }
}

// ---------------------------------------------------------------------------
// Fill Vt row d=8 with bf16 1.0 (ones column -> denominator via MFMA).
// Vt global layout: [bh][9][2048] bf16 (dword rows of 1024).
// ---------------------------------------------------------------------------
__global__ __launch_bounds__(256)
void ones_kernel(unsigned* __restrict__ Vtg)
{
  const int bh = blockIdx.x;
  unsigned* row = Vtg + ((size_t)bh * 9 + 8) * 1024;
  #pragma unroll
  for (int it = 0; it < 4; ++it) row[threadIdx.x + it * 256] = 0x3F803F80u;
}

// ---------------------------------------------------------------------------
// out = X @ W^T + b with pre-transposed WT. 32 rows x 128 cols per block.
// mode 0: Q scaled by QNEG -> bf16 Qb[bh][s][8]
// mode 1: K -> bf16 Kb[bh][s][8]
// mode 2: V -> bf16 Vt[bh][d(0..8)][s]   (transposed scatter; row 8 = ones)
// mode 3: fp32 row-major [rows][128] (final output)
// ---------------------------------------------------------------------------
__device__ __forceinline__
void proj_body(const float* __restrict__ X, const float* __restrict__ WT,
               const float* __restrict__ bias, void* __restrict__ out, int mode)
{
  __shared__ float xs[32][EDIM];                  // 16 KB
  const int tid = threadIdx.x;
  const int row0 = blockIdx.x * 32;

  const float4* src = (const float4*)(X + row0 * EDIM);
  float4* dst = (float4*)(&xs[0][0]);
  #pragma unroll
  for (int t = 0; t < 4; ++t) dst[tid + t * 256] = src[tid + t * 256];
  __syncthreads();

  const int tc = tid & 31;
  const int tr = tid >> 5;                        // 0..7 (4 rows each)
  const int col0 = tc * 4;

  float acc[4][4];
  #pragma unroll
  for (int r = 0; r < 4; ++r)
    #pragma unroll
    for (int c = 0; c < 4; ++c) acc[r][c] = 0.f;

  #pragma unroll 2
  for (int ib = 0; ib < EDIM / 4; ++ib) {
    const float4 w0 = *(const float4*)(WT + (4 * ib + 0) * EDIM + col0);
    const float4 w1 = *(const float4*)(WT + (4 * ib + 1) * EDIM + col0);
    const float4 w2 = *(const float4*)(WT + (4 * ib + 2) * EDIM + col0);
    const float4 w3 = *(const float4*)(WT + (4 * ib + 3) * EDIM + col0);
    #pragma unroll
    for (int r = 0; r < 4; ++r) {
      const float4 x4 = *(const float4*)(&xs[tr * 4 + r][ib * 4]);  // b128 broadcast
      acc[r][0] += x4.x * w0.x + x4.y * w1.x + x4.z * w2.x + x4.w * w3.x;
      acc[r][1] += x4.x * w0.y + x4.y * w1.y + x4.z * w2.y + x4.w * w3.y;
      acc[r][2] += x4.x * w0.z + x4.y * w1.z + x4.z * w2.z + x4.w * w3.z;
      acc[r][3] += x4.x * w0.w + x4.y * w1.w + x4.z * w2.w + x4.w * w3.w;
    }
  }

  const float4 b4 = *(const float4*)(bias + col0);
  #pragma unroll
  for (int r = 0; r < 4; ++r) {
    const int grow = row0 + tr * 4 + r;
    const float4 o = make_float4(acc[r][0] + b4.x, acc[r][1] + b4.y,
                                 acc[r][2] + b4.z, acc[r][3] + b4.w);
    if (mode == 3) {
      *(float4*)((float*)out + (size_t)grow * EDIM + col0) = o;
    } else {
      const int b = grow >> 11, s = grow & (SEQ - 1);
      const int h = col0 >> 3, d0 = col0 & 7;     // d0 in {0,4}
      const size_t bhs = (size_t)(b * NHEAD + h) * SEQ + s;
      if (mode == 0) {
        uint2 p;
        p.x = pk_bf16(o.x * QNEG, o.y * QNEG);
        p.y = pk_bf16(o.z * QNEG, o.w * QNEG);
        *(uint2*)((unsigned*)out + bhs * 4 + (d0 >> 1)) = p;
      } else if (mode == 1) {
        uint2 p;
        p.x = pk_bf16(o.x, o.y);
        p.y = pk_bf16(o.z, o.w);
        *(uint2*)((unsigned*)out + bhs * 4 + (d0 >> 1)) = p;
      } else {
        unsigned short* vt = (unsigned short*)out;
        const size_t base = ((size_t)(b * NHEAD + h)) * 9;
        const float oo[4] = {o.x, o.y, o.z, o.w};
        #pragma unroll
        for (int c = 0; c < 4; ++c)
          vt[(base + d0 + c) * SEQ + s] = pk_bf16_1(oo[c]);
      }
    }
  }
}

__global__ __launch_bounds__(256)
void qkv_kernel(const float* __restrict__ X, const float* __restrict__ WT,
                const float* __restrict__ bq, const float* __restrict__ bk,
                const float* __restrict__ bv,
                unsigned* __restrict__ qb, unsigned* __restrict__ kb,
                unsigned* __restrict__ vtg)
{
  const int m = blockIdx.y;
  const float* wt   = WT + m * EDIM * EDIM;
  const float* bias = (m == 0) ? bq : (m == 1) ? bk : bv;
  void* out         = (m == 0) ? (void*)qb : (m == 1) ? (void*)kb : (void*)vtg;
  proj_body(X, wt, bias, out, m);
}

__global__ __launch_bounds__(256)
void oproj_kernel(const float* __restrict__ A, const float* __restrict__ WTo,
                  const float* __restrict__ bo, float* __restrict__ out)
{
  proj_body(A, WTo, bo, (void*)out, 3);
}

// ---------------------------------------------------------------------------
// Causal sigmoid-attention v5: MFMA.
// S^T = mfma_16x16x32_bf16(A=K-rows, B=Q-rows)  -> C[key][q] (row=4*quad+reg,
// col=lane&15). Sigmoid elementwise; the C-layout of S^T IS the B-layout of
// mfma_16x16x16 (k=4*quad+j, n=lane&15), so PV needs NO transform:
// out^T = mfma_16x16x16_bf16(A=Vt-frag [d][key], B=P^T, acc).
// Vt row 8 is all-ones -> acc row 8 accumulates the denominator.
// Block = (bh, 256 q-rows); wave w owns rows 64w..64w+63 (4 q-tiles), sweeps
// its full causal key range from LDS-staged K/Vt; no inter-wave reduction.
// Launch order pairs heavy+light blocks (mb 7,6,5,4 then 0,1,2,3).
// ---------------------------------------------------------------------------
__global__ __launch_bounds__(256)
void attn_kernel(const unsigned* __restrict__ Qb, const unsigned* __restrict__ Kb,
                 const unsigned* __restrict__ Vtg, float* __restrict__ out)
{
  __shared__ uint4 ldsK[2048];                    // 32 KB: K rows [key][8 bf16]
  __shared__ unsigned short ldsVt[9 * 2064];      // 36.3 KB: Vt rows [d][key]

  const int bi   = blockIdx.x;
  const int bh   = bi & 63;
  const int g    = (bi & 255) >> 6;
  const int mb   = (bi < 256) ? (7 - g) : g;      // pairs (7,0),(6,1),(5,2),(4,3)
  const int tid  = threadIdx.x;
  const int w    = tid >> 6;
  const int lane = tid & 63;
  const int laneq = lane & 15;
  const int quad  = lane >> 4;
  const int kmax  = 256 * (mb + 1);

  // ---- cooperative stage: K rows [0,kmax), Vt rows 0..8 cols [0,kmax) ----
  const uint4* Kg = (const uint4*)Kb + (size_t)bh * 2048;
  for (int r = tid; r < kmax; r += 256) ldsK[r] = Kg[r];
  const uint4* Vg = (const uint4*)Vtg + (size_t)bh * 9 * 256;
  const int c8 = kmax >> 3;                       // uint4 per Vt row
  #pragma unroll
  for (int d = 0; d < 9; ++d)
    for (int c = tid; c < c8; c += 256)
      *(uint4*)((char*)ldsVt + d * 4128 + c * 16) = Vg[d * 256 + c];

  // ---- Q B-frags (one per q-tile); zero quads 1..3 (pads K contraction) ----
  const int wq0 = 256 * mb + 64 * w;
  const uint4* Qg = (const uint4*)Qb + (size_t)bh * 2048;
  short8v qf[4];
  #pragma unroll
  for (int qi = 0; qi < 4; ++qi) {
    U16x8 u;
    uint4 raw = Qg[wq0 + 16 * qi + laneq];
    u.u = (lane < 16) ? raw : make_uint4(0u, 0u, 0u, 0u);
    qf[qi] = u.s;
  }
  __syncthreads();

  float4v acc[4];
  #pragma unroll
  for (int qi = 0; qi < 4; ++qi) acc[qi] = (float4v){0.f, 0.f, 0.f, 0.f};

  const int t0   = wq0 >> 4;
  const int tend = t0 + 4;
  const int vrow = (laneq < 8) ? laneq : 8;       // clamp: rows 9..15 read ones
  const unsigned short* vb = ldsVt + vrow * 2064 + 4 * quad;

  uint4 kraw = ldsK[laneq];                       // prefetch t=0
  uint2 vraw = *(const uint2*)(vb);

  for (int t = 0; t < tend; ++t) {
    const uint4 kcur = kraw;
    const uint2 vcur = vraw;
    kraw = ldsK[16 * (t + 1) + laneq];            // stays inside LDS alloc
    vraw = *(const uint2*)(vb + 16 * (t + 1));
    U16x8 kf; kf.u = kcur;
    U16x4 vf; vf.u = vcur;
    const int qlo = t - t0;                       // may be negative
    #pragma unroll
    for (int qi = 0; qi < 4; ++qi) {
      if (qi < qlo) continue;                     // fully-masked tile: skip
      const bool diag = (qi == qlo);
      float4v z = {0.f, 0.f, 0.f, 0.f};
      float4v st = __builtin_amdgcn_mfma_f32_16x16x32_bf16(kf.s, qf[qi], z, 0, 0, 0);
      unsigned rb[4];
      #pragma unroll
      for (int r = 0; r < 4; ++r) {
        float s = RCPF(1.f + EXP2F(st[r]));       // Q carries -scale*log2e
        if (diag) s = (4 * quad + r <= laneq) ? s : 0.f;  // exact: sigma(-1e9)==0
        rb[r] = __float_as_uint(s) + 0x8000u;     // round-half-up to bf16
      }
      U16x4 p;
      p.u.x = __builtin_amdgcn_perm(rb[1], rb[0], 0x07060302u);
      p.u.y = __builtin_amdgcn_perm(rb[3], rb[2], 0x07060302u);
      acc[qi] = MFMA_PV(vf.s, p.s, acc[qi]);      // out^T += Vt-frag * P^T
    }
  }

  // ---- epilogue: normalize by acc row 8 (den), store out[q][d] ----
  const int b = bh >> 4, h = bh & 15;
  #pragma unroll
  for (int qi = 0; qi < 4; ++qi) {
    const int di = __builtin_amdgcn_ds_bpermute((32 + laneq) << 2,
                                                __float_as_int(acc[qi][0]));
    const float inv = RCPF(__int_as_float(di));   // den > 0
    if (lane < 32) {                              // quads 0,1 hold d=0..7
      const float4 o = make_float4(acc[qi][0] * inv, acc[qi][1] * inv,
                                   acc[qi][2] * inv, acc[qi][3] * inv);
      const int row = wq0 + 16 * qi + laneq;
      *(float4*)(out + ((size_t)(b * SEQ + row)) * EDIM + h * HDIM + 4 * quad) = o;
    }
  }
}

// ---------------------------------------------------------------------------
extern "C" void kernel_launch(void* const* d_in, const int* in_sizes, int n_in,
                              void* d_out, int out_size, void* d_ws, size_t ws_size,
                              hipStream_t stream)
{
  const float* x  = (const float*)d_in[0];
  const float* Wq = (const float*)d_in[1];
  const float* bq = (const float*)d_in[2];
  const float* Wk = (const float*)d_in[3];
  const float* bk = (const float*)d_in[4];
  const float* Wv = (const float*)d_in[5];
  const float* bv = (const float*)d_in[6];
  const float* Wo = (const float*)d_in[7];
  const float* bo = (const float*)d_in[8];

  float* ws = (float*)d_ws;
  // dword layout: WT 65536f | attn 1048576f | Qb 524288 | Kb 524288 | Vtg 589824
  float*    WT   = ws;
  float*    attn = ws + 65536;
  unsigned* Qb   = (unsigned*)(ws + 65536 + 1048576);
  unsigned* Kb   = Qb + (size_t)524288;
  unsigned* Vtg  = Kb + (size_t)524288;

  transpose4_kernel<<<dim3(8, 4), 256, 0, stream>>>(Wq, Wk, Wv, Wo, WT);
  ones_kernel<<<dim3(64), 256, 0, stream>>>(Vtg);
  qkv_kernel<<<dim3(NROW / 32, 3), 256, 0, stream>>>(x, WT, bq, bk, bv, Qb, Kb, Vtg);
  attn_kernel<<<dim3(512), 256, 0, stream>>>(Qb, Kb, Vtg, attn);
  oproj_kernel<<<dim3(NROW / 32), 256, 0, stream>>>(attn, WT + 3 * EDIM * EDIM, bo,
                                                    (float*)d_out);
}

// Round 6
// 160.217 us; speedup vs baseline: 1.4283x; 1.4283x over previous
//
#include <hip/hip_runtime.h>
#include <math.h>

#define EDIM 128
#define NHEAD 16
#define HDIM 8
#define SEQ 2048
#define BATCH 4
#define NROW (BATCH*SEQ)            // 8192
// -scale*log2(e): folded into Q at projection time so sigmoid = rcp(1+exp2(dot))
#define QNEG (-0.35355339059327373f * 1.4426950408889634f)

#if __has_builtin(__builtin_amdgcn_exp2f)
#define EXP2F(x) __builtin_amdgcn_exp2f(x)
#else
#define EXP2F(x) exp2f(x)
#endif
#define RCPF(x) __builtin_amdgcn_rcpf(x)

typedef __attribute__((ext_vector_type(8))) short short8v;
typedef __attribute__((ext_vector_type(4))) short short4v;
typedef __attribute__((ext_vector_type(4))) float float4v;

union U16x8 { uint4 u; short8v s; };
union U16x4 { uint2 u; short4v s; };

#if __has_builtin(__builtin_amdgcn_mfma_f32_16x16x16bf16_1k)
#define MFMA_PV(a,b,c) __builtin_amdgcn_mfma_f32_16x16x16bf16_1k(a,b,c,0,0,0)
#else
static __device__ __forceinline__ float4v mfma_pv_asm(short4v a, short4v b, float4v c) {
  float4v d;
  asm("v_mfma_f32_16x16x16_bf16 %0, %1, %2, %3" : "=v"(d) : "v"(a), "v"(b), "v"(c));
  return d;
}
#define MFMA_PV(a,b,c) mfma_pv_asm(a,b,c)
#endif

// pack two floats to bf16x2, round-to-nearest-even (values finite)
__device__ __forceinline__ unsigned pk_bf16(float a, float b) {
  unsigned ua = __float_as_uint(a), ub = __float_as_uint(b);
  unsigned lo = (ua + 0x7fffu + ((ua >> 16) & 1u)) >> 16;
  unsigned hi = (ub + 0x7fffu + ((ub >> 16) & 1u)) & 0xffff0000u;
  return lo | hi;
}

// ---------------------------------------------------------------------------
// Transpose the 4 weight matrices W[j][i] -> WT[i][j].
// ---------------------------------------------------------------------------
__global__ __launch_bounds__(256)
void transpose4_kernel(const float* __restrict__ W0, const float* __restrict__ W1,
                       const float* __restrict__ W2, const float* __restrict__ W3,
                       float* __restrict__ WT)
{
  const float* W = (blockIdx.y == 0) ? W0 : (blockIdx.y == 1) ? W1
                 : (blockIdx.y == 2) ? W2 : W3;
  float* out = WT + blockIdx.y * EDIM * EDIM;
  const int i0 = blockIdx.x * 16;
  #pragma unroll
  for (int it = 0; it < 8; ++it) {
    int f = threadIdx.x + it * 256;
    int i = i0 + (f >> 7);
    int j = f & 127;
    out[i * EDIM + j] = W[j * EDIM + i];
  }
}

// ---------------------------------------------------------------------------
// out = X @ W^T + b with pre-transposed WT. 32 rows x 128 cols per block.
// mode 0: Q scaled by QNEG -> bf16 [bh][s][8]
// mode 1/2: K / V -> bf16 [bh][s][8]   (coalesced uint2 stores)
// mode 3: fp32 row-major [rows][128] (final output)
// ---------------------------------------------------------------------------
__device__ __forceinline__
void proj_body(const float* __restrict__ X, const float* __restrict__ WT,
               const float* __restrict__ bias, void* __restrict__ out, int mode)
{
  __shared__ float xs[32][EDIM];                  // 16 KB
  const int tid = threadIdx.x;
  const int row0 = blockIdx.x * 32;

  const float4* src = (const float4*)(X + row0 * EDIM);
  float4* dst = (float4*)(&xs[0][0]);
  #pragma unroll
  for (int t = 0; t < 4; ++t) dst[tid + t * 256] = src[tid + t * 256];
  __syncthreads();

  const int tc = tid & 31;
  const int tr = tid >> 5;                        // 0..7 (4 rows each)
  const int col0 = tc * 4;

  float acc[4][4];
  #pragma unroll
  for (int r = 0; r < 4; ++r)
    #pragma unroll
    for (int c = 0; c < 4; ++c) acc[r][c] = 0.f;

  #pragma unroll 2
  for (int ib = 0; ib < EDIM / 4; ++ib) {
    const float4 w0 = *(const float4*)(WT + (4 * ib + 0) * EDIM + col0);
    const float4 w1 = *(const float4*)(WT + (4 * ib + 1) * EDIM + col0);
    const float4 w2 = *(const float4*)(WT + (4 * ib + 2) * EDIM + col0);
    const float4 w3 = *(const float4*)(WT + (4 * ib + 3) * EDIM + col0);
    #pragma unroll
    for (int r = 0; r < 4; ++r) {
      const float4 x4 = *(const float4*)(&xs[tr * 4 + r][ib * 4]);  // b128 broadcast
      acc[r][0] += x4.x * w0.x + x4.y * w1.x + x4.z * w2.x + x4.w * w3.x;
      acc[r][1] += x4.x * w0.y + x4.y * w1.y + x4.z * w2.y + x4.w * w3.y;
      acc[r][2] += x4.x * w0.z + x4.y * w1.z + x4.z * w2.z + x4.w * w3.z;
      acc[r][3] += x4.x * w0.w + x4.y * w1.w + x4.z * w2.w + x4.w * w3.w;
    }
  }

  const float4 b4 = *(const float4*)(bias + col0);
  #pragma unroll
  for (int r = 0; r < 4; ++r) {
    const int grow = row0 + tr * 4 + r;
    const float4 o = make_float4(acc[r][0] + b4.x, acc[r][1] + b4.y,
                                 acc[r][2] + b4.z, acc[r][3] + b4.w);
    if (mode == 3) {
      *(float4*)((float*)out + (size_t)grow * EDIM + col0) = o;
    } else {
      const int b = grow >> 11, s = grow & (SEQ - 1);
      const int h = col0 >> 3, d0 = col0 & 7;     // d0 in {0,4}
      const size_t bhs = (size_t)(b * NHEAD + h) * SEQ + s;
      uint2 p;
      if (mode == 0) {
        p.x = pk_bf16(o.x * QNEG, o.y * QNEG);
        p.y = pk_bf16(o.z * QNEG, o.w * QNEG);
      } else {
        p.x = pk_bf16(o.x, o.y);
        p.y = pk_bf16(o.z, o.w);
      }
      *(uint2*)((unsigned*)out + bhs * 4 + (d0 >> 1)) = p;
    }
  }
}

__global__ __launch_bounds__(256)
void qkv_kernel(const float* __restrict__ X, const float* __restrict__ WT,
                const float* __restrict__ bq, const float* __restrict__ bk,
                const float* __restrict__ bv,
                unsigned* __restrict__ qb, unsigned* __restrict__ kb,
                unsigned* __restrict__ vb)
{
  const int m = blockIdx.y;
  const float* wt   = WT + m * EDIM * EDIM;
  const float* bias = (m == 0) ? bq : (m == 1) ? bk : bv;
  void* out         = (m == 0) ? (void*)qb : (m == 1) ? (void*)kb : (void*)vb;
  proj_body(X, wt, bias, out, m);
}

__global__ __launch_bounds__(256)
void oproj_kernel(const float* __restrict__ A, const float* __restrict__ WTo,
                  const float* __restrict__ bo, float* __restrict__ out)
{
  proj_body(A, WTo, bo, (void*)out, 3);
}

// ---------------------------------------------------------------------------
// One 16q x 16k MFMA step.
// S^T = mfma_16x16x32_bf16(A=K-rows, B=Q-frag) -> C[key][q] (row=4*quad+reg,
// col=laneq). Sigmoid elementwise; C-layout of S^T IS the B-layout of
// mfma_16x16x16 (k=4*quad+j, n=laneq) -> PV with NO transform:
// out^T += mfma_16x16x16_bf16(A=Vt-frag [d][key], B=P^T).
// ---------------------------------------------------------------------------
template<bool DIAG>
__device__ __forceinline__
float4v attn_step(short8v kf, short8v qf, short4v vf, float4v acc,
                  int laneq, int quad)
{
  const float4v z = {0.f, 0.f, 0.f, 0.f};
  float4v st = __builtin_amdgcn_mfma_f32_16x16x32_bf16(kf, qf, z, 0, 0, 0);
  unsigned rb[4];
  #pragma unroll
  for (int r = 0; r < 4; ++r) {
    float s = RCPF(1.f + EXP2F(st[r]));           // Q carries -scale*log2e
    if (DIAG) s = (4 * quad + r <= laneq) ? s : 0.f;  // exact: sigma(-1e9)==0
    rb[r] = __float_as_uint(s) + 0x8000u;         // round-half-up to bf16
  }
  U16x4 p;
  p.u.x = __builtin_amdgcn_perm(rb[1], rb[0], 0x07060302u);
  p.u.y = __builtin_amdgcn_perm(rb[3], rb[2], 0x07060302u);
  return MFMA_PV(vf, p.s, acc);
}

// transpose-commit: lane holds V rows (keys 2*lane, 2*lane+1) as bf16x8;
// write Vt[d][2*lane..2*lane+1] as one b32 per d (conflict-free: 1 lane/bank)
__device__ __forceinline__
void commitV(unsigned short* __restrict__ vtb, int lane,
             const uint4& v0, const uint4& v1)
{
  const unsigned* a = (const unsigned*)&v0;
  const unsigned* b = (const unsigned*)&v1;
  #pragma unroll
  for (int d = 0; d < 8; ++d) {
    const unsigned w = __builtin_amdgcn_perm(b[d >> 1], a[d >> 1],
                                             (d & 1) ? 0x07060302u : 0x05040100u);
    *(unsigned*)((char*)vtb + d * 272 + lane * 4) = w;
  }
}

// ---------------------------------------------------------------------------
// Causal sigmoid-attention v6: balanced 1-wave blocks.
// Wave = fold-pair of q-tiles (L=g, H=127-g): exactly (g+1)+(128-g)=129
// key-tile steps per wave -> perfect balance. K/V staged in wave-private
// double-buffered 128-key LDS chunks (9 KB/block -> 16 blocks/CU, 50% occ),
// V transposed into Vt[d][key] (pitch 136 shorts) during staging; row d=8 is
// ones -> acc row 8 = denominator. No barriers anywhere.
// blockIdx = g*64 + bh -> XCD = bh%8 (KV L2 locality).
// ---------------------------------------------------------------------------
__global__ __launch_bounds__(64, 4)
void attn_kernel(const unsigned* __restrict__ Qb, const unsigned* __restrict__ Kb,
                 const unsigned* __restrict__ Vb, float* __restrict__ out)
{
  __shared__ uint4 ldsK[2][128];                  // 4 KB
  __shared__ unsigned short ldsVt[2][1228];       // 2x2456 B (pitch 136, 9 rows)

  const int bh    = blockIdx.x & 63;
  const int g     = blockIdx.x >> 6;              // 0..63
  const int lane  = threadIdx.x;
  const int laneq = lane & 15;
  const int quad  = lane >> 4;
  const int L = g, H = 127 - g;                   // q-tile indices (16 rows each)

  const uint4* Kg = (const uint4*)Kb + (size_t)bh * 2048;
  const uint4* Vg = (const uint4*)Vb + (size_t)bh * 2048;
  const uint4* Qg = (const uint4*)Qb + (size_t)bh * 2048;

  // ones rows (d=8) for both buffers; V commits only touch d<8
  *(unsigned*)((char*)&ldsVt[0][8 * 136] + lane * 4) = 0x3F803F80u;
  *(unsigned*)((char*)&ldsVt[1][8 * 136] + lane * 4) = 0x3F803F80u;

  // Q B-frags: zero lanes>=16 (pads the K=32 contraction; K-frag quads 1..3
  // hold garbage but multiply by these zeros)
  U16x8 qfl, qfh;
  {
    const uint4 rl = Qg[16 * L + laneq];
    const uint4 rh = Qg[16 * H + laneq];
    qfl.u = (lane < 16) ? rl : make_uint4(0u, 0u, 0u, 0u);
    qfh.u = (lane < 16) ? rh : make_uint4(0u, 0u, 0u, 0u);
  }

  float4v accL = {0.f, 0.f, 0.f, 0.f};
  float4v accH = {0.f, 0.f, 0.f, 0.f};

  const int CH = H >> 3;                          // last chunk index
  uint4 kA, kB, v0, v1;

  // prologue: stage chunk 0
  kA = Kg[lane];          kB = Kg[64 + lane];
  v0 = Vg[2 * lane];      v1 = Vg[2 * lane + 1];
  ldsK[0][lane] = kA;     ldsK[0][64 + lane] = kB;
  commitV(ldsVt[0], lane, v0, v1);

  const int vrow = (laneq < 8) ? laneq : 8;       // d; rows 9..15 read ones

  for (int c = 0; c <= CH; ++c) {
    const int cb = c & 1;
    if (c < CH) {                                 // prefetch next chunk -> regs
      const int off = 128 * (c + 1);
      kA = Kg[off + lane];         kB = Kg[off + 64 + lane];
      v0 = Vg[off + 2 * lane];     v1 = Vg[off + 2 * lane + 1];
    }
    const uint4* kbuf = ldsK[cb];
    const unsigned short* vb2 = ldsVt[cb] + vrow * 136 + 4 * quad;
    #pragma unroll
    for (int tloc = 0; tloc < 8; ++tloc) {
      const int t = 8 * c + tloc;
      if (t > H) break;                           // only in the last chunk
      U16x8 kf; kf.u = kbuf[16 * tloc + laneq];   // broadcast b128
      U16x4 vf; vf.u = *(const uint2*)(vb2 + 16 * tloc);
      if (t <= L) {
        if (t == L) accL = attn_step<true >(kf.s, qfl.s, vf.s, accL, laneq, quad);
        else        accL = attn_step<false>(kf.s, qfl.s, vf.s, accL, laneq, quad);
      }
      if (t == H)   accH = attn_step<true >(kf.s, qfh.s, vf.s, accH, laneq, quad);
      else          accH = attn_step<false>(kf.s, qfh.s, vf.s, accH, laneq, quad);
    }
    if (c < CH) {                                 // commit prefetched chunk
      const int nb = cb ^ 1;
      ldsK[nb][lane] = kA;  ldsK[nb][64 + lane] = kB;
      commitV(ldsVt[nb], lane, v0, v1);
    }
  }

  // epilogue: den = acc row 8 (lives in quad 2, reg 0); normalize, store
  const int b_ = bh >> 4, h = bh & 15;
  {
    const int di = __builtin_amdgcn_ds_bpermute((32 + laneq) << 2,
                                                __float_as_int(accL[0]));
    const float inv = RCPF(__int_as_float(di));
    if (lane < 32) {
      const float4 o = make_float4(accL[0] * inv, accL[1] * inv,
                                   accL[2] * inv, accL[3] * inv);
      const int row = 16 * L + laneq;
      *(float4*)(out + ((size_t)(b_ * SEQ + row)) * EDIM + h * HDIM + 4 * quad) = o;
    }
  }
  {
    const int di = __builtin_amdgcn_ds_bpermute((32 + laneq) << 2,
                                                __float_as_int(accH[0]));
    const float inv = RCPF(__int_as_float(di));
    if (lane < 32) {
      const float4 o = make_float4(accH[0] * inv, accH[1] * inv,
                                   accH[2] * inv, accH[3] * inv);
      const int row = 16 * H + laneq;
      *(float4*)(out + ((size_t)(b_ * SEQ + row)) * EDIM + h * HDIM + 4 * quad) = o;
    }
  }
}

// ---------------------------------------------------------------------------
extern "C" void kernel_launch(void* const* d_in, const int* in_sizes, int n_in,
                              void* d_out, int out_size, void* d_ws, size_t ws_size,
                              hipStream_t stream)
{
  const float* x  = (const float*)d_in[0];
  const float* Wq = (const float*)d_in[1];
  const float* bq = (const float*)d_in[2];
  const float* Wk = (const float*)d_in[3];
  const float* bk = (const float*)d_in[4];
  const float* Wv = (const float*)d_in[5];
  const float* bv = (const float*)d_in[6];
  const float* Wo = (const float*)d_in[7];
  const float* bo = (const float*)d_in[8];

  float* ws = (float*)d_ws;
  // layout: WT 65536 f | attn 1048576 f | Qb, Kb, Vb 524288 dwords each
  float*    WT   = ws;
  float*    attn = ws + 65536;
  unsigned* Qb   = (unsigned*)(ws + 65536 + 1048576);
  unsigned* Kb   = Qb + (size_t)524288;
  unsigned* Vb   = Kb + (size_t)524288;

  transpose4_kernel<<<dim3(8, 4), 256, 0, stream>>>(Wq, Wk, Wv, Wo, WT);
  qkv_kernel<<<dim3(NROW / 32, 3), 256, 0, stream>>>(x, WT, bq, bk, bv, Qb, Kb, Vb);
  attn_kernel<<<dim3(4096), 64, 0, stream>>>(Qb, Kb, Vb, attn);
  oproj_kernel<<<dim3(NROW / 32), 256, 0, stream>>>(attn, WT + 3 * EDIM * EDIM, bo,
                                                    (float*)d_out);
}